// Round 3
// baseline (630.542 us; speedup 1.0000x reference)
//
#include <hip/hip_runtime.h>

// Problem constants (B=64, T=1000, IN=OUT=512)
//   outputs  zs     [64,1000,512]        -> d_out[0 .. 32768000)
//   states   v_full [64,1001,512]        -> d_out[32768000 .. 65568768)
//   states   z_full [64,1001,512]        -> d_out[65568768 .. 98369536)
#define SV_OFF 32768000
#define SZ_OFF 65568768

typedef __attribute__((ext_vector_type(8))) short bf16x8;
typedef __attribute__((ext_vector_type(4))) float f32x4;

__device__ __forceinline__ unsigned short f2bf(float f) {
  union { float f; unsigned u; } x; x.f = f;
  unsigned r = x.u + 0x7fffu + ((x.u >> 16) & 1u);  // RNE
  return (unsigned short)(r >> 16);
}

__device__ __forceinline__ void gl_lds16(const void* g, void* l) {
  __builtin_amdgcn_global_load_lds(
      (const __attribute__((address_space(1))) unsigned int*)g,
      (__attribute__((address_space(3))) unsigned int*)l, 16, 0, 0);
}

// ---------------------------------------------------------------- prep
__global__ __launch_bounds__(256) void prep(const float* __restrict__ W,
                                            unsigned short* __restrict__ Wb,
                                            int* __restrict__ flags) {
  const int idx = blockIdx.x * 256 + threadIdx.x;
  if (idx < 512 * 512) Wb[idx] = f2bf(W[idx]);
  if (idx < 64) flags[idx] = 0;
}

// ---------------------------------------------------------------- fused GEMM+scan
// Persistent block per (b, 64-wide o-slice). Per 128-t tile: MFMA GEMM with
// A read DIRECTLY from f32 x (reg-staged, converted in-register, T14 split:
// issue loads early / convert+ds_write late), B via global_load_lds from
// L2-resident Wb. cur tile lives only in LDS; then exact sequential scan.
// Grid dim3(64,8): all 8 o-slices of batch b land on XCD b%8, so x[b] is
// fetched from HBM once and reused 8x via that XCD's L2.
__global__ __launch_bounds__(256, 2) void fused(
    const float* __restrict__ x,             // [64,1000,512] f32
    const unsigned short* __restrict__ Wb,   // [512,512] bf16
    const float* __restrict__ bias,
    const float* __restrict__ decay,
    float* __restrict__ out,
    int* __restrict__ flags) {
  __shared__ unsigned short As[2][128][40];  // 20 KB (A k-step dbuf, +8 pad)
  __shared__ unsigned short Bs[2][64][32];   //  8 KB (B k-step dbuf, gl_lds-linear)
  __shared__ float cs[128][64];              // 32 KB (cur tile, swizzled)

  const int b    = blockIdx.x;
  const int o0   = blockIdx.y * 64;
  const int tid  = threadIdx.x;
  const int wave = tid >> 6;
  const int lane = tid & 63;
  const int lr = lane & 15;
  const int lq = lane >> 4;
  const int wr = wave >> 1;   // t-half of tile (0..1)
  const int wc = wave & 1;    // o-half of slice (0..1)

  // A staging: 256 threads cover 128 rows x 32 floats; each thread 4 rows x 4 floats
  const int ar = tid >> 3;          // 0..31 (row within 32-row group)
  const int ac = (tid & 7) * 4;     // float col within the 32-wide k-slice
  const float* xb = x + (size_t)b * 512000;
  // B staging: 256 threads x 16B cover 64 rows x 64B (lane-linear LDS dest)
  const int br  = tid >> 2;         // 0..63
  const int bcb = (tid & 3) * 16;   // byte within 64B k-slice
  const char* bbase = (const char*)Wb + (size_t)o0 * 1024;

  float4 nxt[4];

  // issue next k-step's A loads into regs (clamp tail rows of last tile: they
  // feed only cs rows >=104 which the scan never reads)
#define A_ISSUE(t0s, kks) do {                                                  \
    _Pragma("unroll")                                                           \
    for (int p4 = 0; p4 < 4; ++p4) {                                            \
      int rg = (t0s) + ar + p4 * 32;                                            \
      rg = rg > 999 ? 999 : rg;                                                 \
      nxt[p4] = *(const float4*)(xb + (size_t)rg * 512 + (kks) * 32 + ac);      \
    }                                                                           \
  } while (0)
  // convert + write the staged regs into As[pp] (compiler inserts the vmcnt wait)
#define A_WRITE(pp) do {                                                        \
    _Pragma("unroll")                                                           \
    for (int p4 = 0; p4 < 4; ++p4) {                                            \
      ushort4 h;                                                                \
      h.x = f2bf(nxt[p4].x); h.y = f2bf(nxt[p4].y);                             \
      h.z = f2bf(nxt[p4].z); h.w = f2bf(nxt[p4].w);                             \
      *(ushort4*)(&As[pp][ar + p4 * 32][ac]) = h;                               \
    }                                                                           \
  } while (0)
#define B_STAGE(pp, kks)                                                        \
    gl_lds16(bbase + (size_t)br * 1024 + (kks) * 64 + bcb,                      \
             (char*)(&Bs[pp][0][0]) + tid * 16)

  // scan state (threads 0..63 own one o each; v carried across tiles)
  float v = 0.f, d = 0.f, om = 0.f, bv = 0.f;
  int fl = 0;
  if (tid < 64) {
    d  = decay[o0 + tid];
    om = 1.f - d;
    bv = bias[o0 + tid];
    // t=0 state rows
    __builtin_nontemporal_store(0.f, out + SV_OFF + (size_t)b * 512512 + o0 + tid);
    __builtin_nontemporal_store(0.f, out + SZ_OFF + (size_t)b * 512512 + o0 + tid);
  }

  // prologue: stage (tile 0, k-step 0)
  A_ISSUE(0, 0);
  B_STAGE(0, 0);
  A_WRITE(0);

  int p = 0;
  for (int tile = 0; tile < 8; ++tile) {
    const int t0 = tile * 128;
    f32x4 acc[4][2] = {};
    for (int kk = 0; kk < 16; ++kk) {
      __syncthreads();                   // buf[p] ready (ds_writes + gl_lds drained)
      const bool havenext = (kk < 15) | (tile < 7);
      if (kk < 15) {
        A_ISSUE(t0, kk + 1);             // loads in flight under the MFMAs
        B_STAGE(p ^ 1, kk + 1);
      } else if (tile < 7) {
        A_ISSUE(t0 + 128, 0);
        B_STAGE(p ^ 1, 0);
      }
      bf16x8 af[4], bf[2];
#pragma unroll
      for (int i = 0; i < 4; ++i)
        af[i] = *(const bf16x8*)(&As[p][wr * 64 + i * 16 + lr][lq * 8]);
#pragma unroll
      for (int j = 0; j < 2; ++j)
        bf[j] = *(const bf16x8*)(&Bs[p][wc * 32 + j * 16 + lr][lq * 8]);
#pragma unroll
      for (int i = 0; i < 4; ++i)
#pragma unroll
        for (int j = 0; j < 2; ++j)
          acc[i][j] = __builtin_amdgcn_mfma_f32_16x16x32_bf16(af[i], bf[j], acc[i][j], 0, 0, 0);
      if (havenext) A_WRITE(p ^ 1);      // vmcnt wait + convert after the MFMAs
      p ^= 1;
    }
    // acc -> cur LDS tile. Swizzle col by lq bit0 so both this write (2-way)
    // and the scan read (2-way) stay bank-conflict-free.
#pragma unroll
    for (int i = 0; i < 4; ++i)
#pragma unroll
      for (int j = 0; j < 2; ++j) {
        const int tb = wr * 64 + i * 16 + lq * 4;
        const int cc = (wc * 32 + j * 16 + lr) ^ ((lq & 1) << 4);
#pragma unroll
        for (int r = 0; r < 4; ++r) cs[tb + r][cc] = acc[i][j][r];
      }
    __syncthreads();                     // cur tile visible to wave 0
    if (tid < 64) {
      const int tmax = (tile == 7) ? 104 : 128;   // 1000 = 7*128 + 104
      float* zp = out + ((size_t)b * 1000 + t0) * 512 + o0 + tid;
      float* vp = out + SV_OFF + ((size_t)b * 1001 + t0 + 1) * 512 + o0 + tid;
      float* sp = out + SZ_OFF + ((size_t)b * 1001 + t0 + 1) * 512 + o0 + tid;
      for (int t = 0; t < tmax; t += 4) {
        const int cc = tid ^ (((t >> 2) & 1) << 4);
        float c4[4];
#pragma unroll
        for (int u = 0; u < 4; ++u) c4[u] = cs[t + u][cc];
#pragma unroll
        for (int u = 0; u < 4; ++u) {
          v = d * v + om * (c4[u] + bv);   // exact reference op order (no-spike path)
          const float z = (v >= 1.0f) ? 1.0f : 0.0f;
          fl |= (v >= 1.0f);
          __builtin_nontemporal_store(z, zp + (size_t)(t + u) * 512);
          __builtin_nontemporal_store(v, vp + (size_t)(t + u) * 512);
          __builtin_nontemporal_store(z, sp + (size_t)(t + u) * 512);
        }
      }
    }
    // no barrier here: next tile's first k-step barrier orders scan vs staging
  }
  if (tid < 64 && fl) atomicOr(flags + b, 1);
#undef A_ISSUE
#undef A_WRITE
#undef B_STAGE
}

// ---------------------------------------------------------------- fixup (rare path)
// Self-sufficient: recomputes soma via f32 GEMV (cur is never materialized).
// Only runs when a batch actually spiked on the speculative path (never here).
__global__ __launch_bounds__(512) void scan_fix(const float* __restrict__ x,
                                                const float* __restrict__ W,
                                                const float* __restrict__ bias,
                                                const float* __restrict__ R,
                                                const float* __restrict__ decay,
                                                float* __restrict__ out,
                                                const int* __restrict__ flags) {
  const int b = blockIdx.x;
  if (flags[b] == 0) return;
  const int o = threadIdx.x;
  __shared__ float xs[512];
  __shared__ int cnt;
  __shared__ int list[512];
  const float d = decay[o];
  const float om = 1.f - d;
  float v = 0.f, z = 0.f;
  const size_t zb  = (size_t)b * 512000 + o;
  const size_t svb = (size_t)b * 512512 + o;
  float* __restrict__ sv = out + SV_OFF;
  float* __restrict__ sz = out + SZ_OFF;
  sv[svb] = 0.f;
  sz[svb] = 0.f;
  if (o == 0) cnt = 0;
  __syncthreads();
  for (int t = 0; t < 1000; ++t) {
    xs[o] = x[((size_t)b * 1000 + t) * 512 + o];
    __syncthreads();
    float soma = bias[o];
    for (int i = 0; i < 512; ++i) soma += xs[i] * W[(size_t)o * 512 + i];
    const int n = cnt;
    for (int i = 0; i < n; ++i) soma += R[(size_t)o * 512 + list[i]];
    v = d * (v * (1.f - z)) + om * soma;
    z = (v >= 1.0f) ? 1.0f : 0.0f;
    out[zb + (size_t)t * 512] = z;
    sv[svb + (size_t)(t + 1) * 512] = v;
    sz[svb + (size_t)(t + 1) * 512] = z;
    __syncthreads();
    if (o == 0) cnt = 0;
    __syncthreads();
    if (z != 0.f) { const int q = atomicAdd(&cnt, 1); list[q] = o; }
    __syncthreads();
  }
}

extern "C" void kernel_launch(void* const* d_in, const int* in_sizes, int n_in,
                              void* d_out, int out_size, void* d_ws, size_t ws_size,
                              hipStream_t stream) {
  (void)in_sizes; (void)n_in; (void)out_size; (void)ws_size;
  const float* x     = (const float*)d_in[0];  // [64,1000,512]
  const float* W     = (const float*)d_in[1];  // [512,512]
  const float* bias  = (const float*)d_in[2];  // [512]
  const float* R     = (const float*)d_in[3];  // [512,512]
  const float* decay = (const float*)d_in[4];  // [512]
  float* out = (float*)d_out;

  char* ws = (char*)d_ws;
  unsigned short* Wb = (unsigned short*)ws;           //  524,288 B
  int* flags         = (int*)(ws + 524288);           //      256 B

  prep<<<1024, 256, 0, stream>>>(W, Wb, flags);
  fused<<<dim3(64, 8), 256, 0, stream>>>(x, Wb, bias, decay, out, flags);
  scan_fix<<<64, 512, 0, stream>>>(x, W, bias, R, decay, out, flags);
}

// Round 4
// 584.572 us; speedup vs baseline: 1.0786x; 1.0786x over previous
//
#include <hip/hip_runtime.h>

// Problem constants (B=64, T=1000, IN=OUT=512)
//   outputs  zs     [64,1000,512]        -> d_out[0 .. 32768000)
//   states   v_full [64,1001,512]        -> d_out[32768000 .. 65568768)
//   states   z_full [64,1001,512]        -> d_out[65568768 .. 98369536)
#define SV_OFF 32768000
#define SZ_OFF 65568768

typedef __attribute__((ext_vector_type(8))) short bf16x8;
typedef __attribute__((ext_vector_type(4))) float f32x4;

__device__ __forceinline__ unsigned short f2bf(float f) {
  union { float f; unsigned u; } x; x.f = f;
  unsigned r = x.u + 0x7fffu + ((x.u >> 16) & 1u);  // RNE
  return (unsigned short)(r >> 16);
}

__device__ __forceinline__ void gl_lds16(const void* g, void* l) {
  __builtin_amdgcn_global_load_lds(
      (const __attribute__((address_space(1))) unsigned int*)g,
      (__attribute__((address_space(3))) unsigned int*)l, 16, 0, 0);
}

// ---------------------------------------------------------------- prep
__global__ __launch_bounds__(256) void prep(const float* __restrict__ W,
                                            unsigned short* __restrict__ Wb,
                                            int* __restrict__ flags) {
  const int idx = blockIdx.x * 256 + threadIdx.x;
  if (idx < 512 * 512) Wb[idx] = f2bf(W[idx]);
  if (idx < 64) flags[idx] = 0;
}

// ---------------------------------------------------------------- cvt_x
__global__ __launch_bounds__(256) void cvt_x(const float* __restrict__ x,
                                             unsigned short* __restrict__ xb) {
  const size_t i = ((size_t)blockIdx.x * 256 + threadIdx.x) * 8;
  const float4 a = *(const float4*)(x + i);
  const float4 b = *(const float4*)(x + i + 4);
  bf16x8 h;
  h[0] = (short)f2bf(a.x); h[1] = (short)f2bf(a.y);
  h[2] = (short)f2bf(a.z); h[3] = (short)f2bf(a.w);
  h[4] = (short)f2bf(b.x); h[5] = (short)f2bf(b.y);
  h[6] = (short)f2bf(b.z); h[7] = (short)f2bf(b.w);
  *(bf16x8*)(xb + i) = h;
}

// ---------------------------------------------------------------- fused GEMM+scan
// 512 blocks x 320 threads. Waves 0-3: MFMA GEMM, 4-buffer depth-3 pipeline
// (counted vmcnt(6), raw s_barrier — T3/T4). Wave 4: scans tile t-1's cs in
// 8-step chunks between the k-step barriers (scan fully hidden under GEMM).
// A/B frag reads use rule-21 both-sides swizzle (pre-swizzled global source,
// linear gl_lds dest, XOR'd read) to cut 8-way bank conflicts to 4-way.
__global__ __launch_bounds__(320, 2) void fused(
    const unsigned short* __restrict__ Ab,   // xb [64000,512] bf16
    const unsigned short* __restrict__ Wb,   // [512,512] bf16
    const float* __restrict__ bias,
    const float* __restrict__ decay,
    float* __restrict__ out,
    int* __restrict__ flags) {
  __shared__ unsigned short As[4][128][32];  // 32 KB (4-deep k-step pipeline)
  __shared__ unsigned short Bs[4][64][32];   // 16 KB
  __shared__ float cs[128][64];              // 32 KB (cur tile, swizzled)

  const int b    = blockIdx.x;
  const int o0   = blockIdx.y * 64;
  const int tid  = threadIdx.x;
  const int lane = tid & 63;
  const int wave = tid >> 6;
  const int lr = lane & 15;
  const int lq = lane >> 4;
  const int wr = wave >> 1;   // t-half of tile (waves 0-3)
  const int wc = wave & 1;    // o-half of slice

  // staging geometry (tid<256): 16 B per thread per gl_lds, linear LDS dest,
  // source column-slot XOR'd by (row&3) so the frag read can un-XOR it.
  const int row0 = tid >> 2;                              // 0..63
  const int scol = ((tid & 3) * 16) ^ ((row0 & 3) << 4);  // swizzled src byte
  const char* abase = (const char*)Ab + (size_t)b * 1000 * 1024;
  const char* bbase = (const char*)Wb + (size_t)o0 * 1024;

  // STAGE(s): global k-step s (tile=s>>4, kk=s&15) into buffer s&3. 3 gl_lds.
#define STAGE(s_) do {                                                          \
    const int t0_ = ((s_) >> 4) * 128;                                          \
    const int kb_ = ((s_) & 15) * 64;                                           \
    const int bf_ = (s_) & 3;                                                   \
    gl_lds16(abase + (size_t)(t0_ + row0) * 1024 + kb_ + scol,                  \
             (char*)&As[bf_][0][0] + tid * 16);                                 \
    gl_lds16(abase + (size_t)(t0_ + 64 + row0) * 1024 + kb_ + scol,             \
             (char*)&As[bf_][0][0] + tid * 16 + 4096);                          \
    gl_lds16(bbase + (size_t)row0 * 1024 + kb_ + scol,                          \
             (char*)&Bs[bf_][0][0] + tid * 16);                                 \
  } while (0)

  // scan state lives on wave 4 (lane o = tid-256 owns channel o0+o)
  float v = 0.f, d = 0.f, om = 0.f, bv = 0.f;
  int fl = 0;
  if (tid >= 256) {
    const int o = tid - 256;
    d  = decay[o0 + o];
    om = 1.f - d;
    bv = bias[o0 + o];
    __builtin_nontemporal_store(0.f, out + SV_OFF + (size_t)b * 512512 + o0 + o);
    __builtin_nontemporal_store(0.f, out + SZ_OFF + (size_t)b * 512512 + o0 + o);
  } else {
    STAGE(0); STAGE(1); STAGE(2);   // prologue: 9 loads in flight
  }

  int s = 0;
  for (int tile = 0; tile < 8; ++tile) {
    f32x4 acc[4][2] = {};
    for (int kk = 0; kk < 16; ++kk, ++s) {
      if (tid < 256)
        asm volatile("s_waitcnt vmcnt(6)" ::: "memory");  // step s done; s+1,s+2 in flight
      __builtin_amdgcn_s_barrier();
      __builtin_amdgcn_sched_barrier(0);
      if (tid < 256) {
        if (s < 125) STAGE(s + 3);   // after barrier: buf (s+3)&3 = (s-1)&3 is free
        const int bf_ = s & 3;
        const int fo = (lq ^ (lr & 3)) * 8;   // un-swizzle the source XOR
        bf16x8 af[4], bq[2];
#pragma unroll
        for (int i = 0; i < 4; ++i)
          af[i] = *(const bf16x8*)(&As[bf_][wr * 64 + i * 16 + lr][fo]);
#pragma unroll
        for (int j = 0; j < 2; ++j)
          bq[j] = *(const bf16x8*)(&Bs[bf_][wc * 32 + j * 16 + lr][fo]);
#pragma unroll
        for (int i = 0; i < 4; ++i)
#pragma unroll
          for (int j = 0; j < 2; ++j)
            acc[i][j] = __builtin_amdgcn_mfma_f32_16x16x32_bf16(af[i], bq[j], acc[i][j], 0, 0, 0);
      } else if (tile > 0) {
        // scan 8 steps of tile-1 (cs holds tile-1 until the tile-end rewrite)
        const int o = tid - 256;
        const int pt0 = (tile - 1) * 128;
        const int tb = kk * 8;
        float* zp = out + ((size_t)b * 1000 + pt0) * 512 + o0 + o;
        float* vp = out + SV_OFF + ((size_t)b * 1001 + pt0 + 1) * 512 + o0 + o;
        float* sp = out + SZ_OFF + ((size_t)b * 1001 + pt0 + 1) * 512 + o0 + o;
#pragma unroll
        for (int u = 0; u < 8; ++u) {
          const int t = tb + u;
          const float c = cs[t][o ^ (((t >> 2) & 1) << 4)];
          v = d * v + om * (c + bv);   // exact reference op order (no-spike path)
          const float z = (v >= 1.0f) ? 1.0f : 0.0f;
          fl |= (v >= 1.0f);
          __builtin_nontemporal_store(z, zp + (size_t)t * 512);
          __builtin_nontemporal_store(v, vp + (size_t)t * 512);
          __builtin_nontemporal_store(z, sp + (size_t)t * 512);
        }
      }
    }
    __builtin_amdgcn_s_barrier();          // wave 4's last chunk done reading cs
    __builtin_amdgcn_sched_barrier(0);
    if (tid < 256) {
      // acc -> cs (col XOR'd by lq&1: write and scan-read both ~2-way)
#pragma unroll
      for (int i = 0; i < 4; ++i)
#pragma unroll
        for (int j = 0; j < 2; ++j) {
          const int tb = wr * 64 + i * 16 + lq * 4;
          const int cc = (wc * 32 + j * 16 + lr) ^ ((lq & 1) << 4);
#pragma unroll
          for (int r = 0; r < 4; ++r) cs[tb + r][cc] = acc[i][j][r];
        }
      asm volatile("s_waitcnt lgkmcnt(0)" ::: "memory");  // cs visible pre-barrier
    }
    __builtin_amdgcn_s_barrier();          // cs(tile) ready for wave 4 next tile
    __builtin_amdgcn_sched_barrier(0);
  }
  // epilogue: wave 4 scans tile 7 (104 valid steps); no barriers after exit paths
  if (tid >= 256) {
    const int o = tid - 256;
    const int pt0 = 896;
    float* zp = out + ((size_t)b * 1000 + pt0) * 512 + o0 + o;
    float* vp = out + SV_OFF + ((size_t)b * 1001 + pt0 + 1) * 512 + o0 + o;
    float* sp = out + SZ_OFF + ((size_t)b * 1001 + pt0 + 1) * 512 + o0 + o;
    for (int t = 0; t < 104; ++t) {
      const float c = cs[t][o ^ (((t >> 2) & 1) << 4)];
      v = d * v + om * (c + bv);
      const float z = (v >= 1.0f) ? 1.0f : 0.0f;
      fl |= (v >= 1.0f);
      __builtin_nontemporal_store(z, zp + (size_t)t * 512);
      __builtin_nontemporal_store(v, vp + (size_t)t * 512);
      __builtin_nontemporal_store(z, sp + (size_t)t * 512);
    }
    if (fl) atomicOr(flags + b, 1);
  }
#undef STAGE
}

// ---------------------------------------------------------------- fixup (rare path)
// Self-sufficient f32 GEMV fallback; runs only if a batch spiked (never here).
__global__ __launch_bounds__(512) void scan_fix(const float* __restrict__ x,
                                                const float* __restrict__ W,
                                                const float* __restrict__ bias,
                                                const float* __restrict__ R,
                                                const float* __restrict__ decay,
                                                float* __restrict__ out,
                                                const int* __restrict__ flags) {
  const int b = blockIdx.x;
  if (flags[b] == 0) return;
  const int o = threadIdx.x;
  __shared__ float xs[512];
  __shared__ int cnt;
  __shared__ int list[512];
  const float d = decay[o];
  const float om = 1.f - d;
  float v = 0.f, z = 0.f;
  const size_t zb  = (size_t)b * 512000 + o;
  const size_t svb = (size_t)b * 512512 + o;
  float* __restrict__ sv = out + SV_OFF;
  float* __restrict__ sz = out + SZ_OFF;
  sv[svb] = 0.f;
  sz[svb] = 0.f;
  if (o == 0) cnt = 0;
  __syncthreads();
  for (int t = 0; t < 1000; ++t) {
    xs[o] = x[((size_t)b * 1000 + t) * 512 + o];
    __syncthreads();
    float soma = bias[o];
    for (int i = 0; i < 512; ++i) soma += xs[i] * W[(size_t)o * 512 + i];
    const int n = cnt;
    for (int i = 0; i < n; ++i) soma += R[(size_t)o * 512 + list[i]];
    v = d * (v * (1.f - z)) + om * soma;
    z = (v >= 1.0f) ? 1.0f : 0.0f;
    out[zb + (size_t)t * 512] = z;
    sv[svb + (size_t)(t + 1) * 512] = v;
    sz[svb + (size_t)(t + 1) * 512] = z;
    __syncthreads();
    if (o == 0) cnt = 0;
    __syncthreads();
    if (z != 0.f) { const int q = atomicAdd(&cnt, 1); list[q] = o; }
    __syncthreads();
  }
}

extern "C" void kernel_launch(void* const* d_in, const int* in_sizes, int n_in,
                              void* d_out, int out_size, void* d_ws, size_t ws_size,
                              hipStream_t stream) {
  (void)in_sizes; (void)n_in; (void)out_size; (void)ws_size;
  const float* x     = (const float*)d_in[0];  // [64,1000,512]
  const float* W     = (const float*)d_in[1];  // [512,512]
  const float* bias  = (const float*)d_in[2];  // [512]
  const float* R     = (const float*)d_in[3];  // [512,512]
  const float* decay = (const float*)d_in[4];  // [512]
  float* out = (float*)d_out;

  char* ws = (char*)d_ws;
  unsigned short* xb = (unsigned short*)ws;                 // 65,536,000 B
  unsigned short* Wb = (unsigned short*)(ws + 65536000);    //    524,288 B
  int* flags         = (int*)(ws + 66060288);               //        256 B
  // (OOB-safe: b=63 tile-7 pad rows read <=24 KB into the Wb region)

  prep<<<1024, 256, 0, stream>>>(W, Wb, flags);
  cvt_x<<<16000, 256, 0, stream>>>(x, xb);
  fused<<<dim3(64, 8), 320, 0, stream>>>(xb, Wb, bias, decay, out, flags);
  scan_fix<<<64, 512, 0, stream>>>(x, W, bias, R, decay, out, flags);
}

// Round 5
// 530.045 us; speedup vs baseline: 1.1896x; 1.1029x over previous
//
#include <hip/hip_runtime.h>

// Problem constants (B=64, T=1000, IN=OUT=512)
//   outputs  zs     [64,1000,512]        -> d_out[0 .. 32768000)
//   states   v_full [64,1001,512]        -> d_out[32768000 .. 65568768)
//   states   z_full [64,1001,512]        -> d_out[65568768 .. 98369536)
#define SV_OFF 32768000
#define SZ_OFF 65568768

typedef __attribute__((ext_vector_type(8))) short bf16x8;
typedef __attribute__((ext_vector_type(4))) float f32x4;

__device__ __forceinline__ unsigned short f2bf(float f) {
  union { float f; unsigned u; } x; x.f = f;
  unsigned r = x.u + 0x7fffu + ((x.u >> 16) & 1u);  // RNE
  return (unsigned short)(r >> 16);
}

__device__ __forceinline__ void gl_lds16(const void* g, void* l) {
  __builtin_amdgcn_global_load_lds(
      (const __attribute__((address_space(1))) unsigned int*)g,
      (__attribute__((address_space(3))) unsigned int*)l, 16, 0, 0);
}

// ---------------------------------------------------------------- prep
__global__ __launch_bounds__(256) void prep(const float* __restrict__ W,
                                            unsigned short* __restrict__ Wb,
                                            int* __restrict__ flags) {
  const int idx = blockIdx.x * 256 + threadIdx.x;
  if (idx < 512 * 512) Wb[idx] = f2bf(W[idx]);
  if (idx < 64) flags[idx] = 0;
}

// ---------------------------------------------------------------- cvt_x
__global__ __launch_bounds__(256) void cvt_x(const float* __restrict__ x,
                                             unsigned short* __restrict__ xb) {
  const size_t i = ((size_t)blockIdx.x * 256 + threadIdx.x) * 8;
  const float4 a = *(const float4*)(x + i);
  const float4 b = *(const float4*)(x + i + 4);
  bf16x8 h;
  h[0] = (short)f2bf(a.x); h[1] = (short)f2bf(a.y);
  h[2] = (short)f2bf(a.z); h[3] = (short)f2bf(a.w);
  h[4] = (short)f2bf(b.x); h[5] = (short)f2bf(b.y);
  h[6] = (short)f2bf(b.z); h[7] = (short)f2bf(b.w);
  *(bf16x8*)(xb + i) = h;
}

// ---------------------------------------------------------------- fused GEMM+scan
// Grid (64,4) = 256 blocks = 1/CU, 512 threads (8 waves, 2Mx4N).
// o-slice widened to 128: A staging traffic halves vs the 64-wide version
// (each xb slab re-staged by 4 blocks instead of 8). Depth-3 gl_lds pipeline,
// uniform vmcnt(4), tail made safe by wrap-around dummy stages. Inline
// tile-end scan by tid<128 (r2 structure — no barrier-coupled scan wave).
__global__ __launch_bounds__(512, 1) void fused(
    const unsigned short* __restrict__ Ab,   // xb [64000,512] bf16
    const unsigned short* __restrict__ Wb,   // [512,512] bf16
    const float* __restrict__ bias,
    const float* __restrict__ decay,
    float* __restrict__ out,
    int* __restrict__ flags) {
  __shared__ unsigned short As[4][128][32];  // 32 KB (4-buf k-step pipeline)
  __shared__ unsigned short Bs[4][128][32];  // 32 KB
  __shared__ float cs[128][128];             // 64 KB (cur tile, lq-XOR swizzled)

  const int b    = blockIdx.x;
  const int o0   = blockIdx.y * 128;
  const int tid  = threadIdx.x;
  const int lane = tid & 63;
  const int wave = tid >> 6;
  const int lr = lane & 15;
  const int lq = lane >> 4;
  const int wr = wave >> 2;   // t-half of tile (0..1)
  const int wc = wave & 3;    // o-quarter of slice (0..3)

  // staging: 512 threads x 16B = one 8KB k-slice per gl_lds, linear LDS dest;
  // global source 16B-slot XOR'd by (row&3) so the frag read can un-XOR it.
  const int row0 = tid >> 2;                              // 0..127
  const int scol = ((tid & 3) * 16) ^ ((row0 & 3) << 4);  // swizzled src byte
  const char* abase = (const char*)Ab + (size_t)b * 1000 * 1024;
  const char* bbase = (const char*)Wb + (size_t)o0 * 1024;

  // STAGE(s): k-step s (tile=s>>4, kk=s&15) into buffer s&3. 2 gl_lds/wave.
#define STAGE(s_) do {                                                          \
    const int t0_ = ((s_) >> 4) * 128;                                          \
    const int kb_ = ((s_) & 15) * 64;                                           \
    const int bf_ = (s_) & 3;                                                   \
    gl_lds16(abase + (size_t)(t0_ + row0) * 1024 + kb_ + scol,                  \
             (char*)&As[bf_][0][0] + tid * 16);                                 \
    gl_lds16(bbase + (size_t)row0 * 1024 + kb_ + scol,                          \
             (char*)&Bs[bf_][0][0] + tid * 16);                                 \
  } while (0)

  // scan state: tid<128 each own channel o0+tid (these threads also do GEMM)
  float v = 0.f, d = 0.f, om = 0.f, bv = 0.f;
  int fl = 0;
  if (tid < 128) {
    d  = decay[o0 + tid];
    om = 1.f - d;
    bv = bias[o0 + tid];
    __builtin_nontemporal_store(0.f, out + SV_OFF + (size_t)b * 512512 + o0 + tid);
    __builtin_nontemporal_store(0.f, out + SZ_OFF + (size_t)b * 512512 + o0 + tid);
  }

  STAGE(0); STAGE(1); STAGE(2);   // prologue: 6 loads/wave in flight

  int s = 0;
  for (int tile = 0; tile < 8; ++tile) {
    f32x4 acc[4][2] = {};
    for (int kk = 0; kk < 16; ++kk, ++s) {
      // step s's 2 loads land when <=4 outstanding (s+1,s+2 still flying)
      asm volatile("s_waitcnt vmcnt(4)" ::: "memory");
      __builtin_amdgcn_s_barrier();
      __builtin_amdgcn_sched_barrier(0);
      // wrap stages (s>=125) are dummies into already-consumed buffers:
      // keeps vmcnt(4) uniform and tail-race-free.
      STAGE((s + 3) & 127);
      const int bf_ = s & 3;
      const int fo = (lq ^ (lr & 3)) * 8;   // un-swizzle the source XOR
      bf16x8 af[4], bq[2];
#pragma unroll
      for (int i = 0; i < 4; ++i)
        af[i] = *(const bf16x8*)(&As[bf_][wr * 64 + i * 16 + lr][fo]);
#pragma unroll
      for (int j = 0; j < 2; ++j)
        bq[j] = *(const bf16x8*)(&Bs[bf_][wc * 32 + j * 16 + lr][fo]);
#pragma unroll
      for (int i = 0; i < 4; ++i)
#pragma unroll
        for (int j = 0; j < 2; ++j)
          acc[i][j] = __builtin_amdgcn_mfma_f32_16x16x32_bf16(af[i], bq[j], acc[i][j], 0, 0, 0);
    }
    // acc -> cs. Writer col' = col ^ (lq<<4): write ~2-way, scan read ~2-way.
    // (lq = (row>>2)&3 for every row this lane writes, so readers recover
    //  col via t: stored col' = col ^ (((t>>2)&3)<<4).)
#pragma unroll
    for (int i = 0; i < 4; ++i)
#pragma unroll
      for (int j = 0; j < 2; ++j) {
        const int tb = wr * 64 + i * 16 + lq * 4;
        const int cc = (wc * 32 + j * 16 + lr) ^ (lq << 4);
#pragma unroll
        for (int r = 0; r < 4; ++r) cs[tb + r][cc] = acc[i][j][r];
      }
    asm volatile("s_waitcnt lgkmcnt(0)" ::: "memory");
    __builtin_amdgcn_s_barrier();          // cs(tile) complete & visible
    __builtin_amdgcn_sched_barrier(0);
    if (tid < 128) {
      const int t0 = tile * 128;
      const int tmax = (tile == 7) ? 104 : 128;   // 1000 = 7*128 + 104
      float* zp = out + ((size_t)b * 1000 + t0) * 512 + o0 + tid;
      float* vp = out + SV_OFF + ((size_t)b * 1001 + t0 + 1) * 512 + o0 + tid;
      float* sp = out + SZ_OFF + ((size_t)b * 1001 + t0 + 1) * 512 + o0 + tid;
      for (int t = 0; t < tmax; t += 4) {
        const int u4 = ((t >> 2) & 3) << 4;
        const float c0 = cs[t + 0][tid ^ u4];
        const float c1 = cs[t + 1][tid ^ u4];
        const float c2 = cs[t + 2][tid ^ u4];
        const float c3 = cs[t + 3][tid ^ u4];
        float cc4[4] = {c0, c1, c2, c3};
#pragma unroll
        for (int u = 0; u < 4; ++u) {
          v = d * v + om * (cc4[u] + bv);  // exact reference op order (no-spike path)
          const float z = (v >= 1.0f) ? 1.0f : 0.0f;
          fl |= (v >= 1.0f);
          __builtin_nontemporal_store(z, zp + (size_t)(t + u) * 512);
          __builtin_nontemporal_store(v, vp + (size_t)(t + u) * 512);
          __builtin_nontemporal_store(z, sp + (size_t)(t + u) * 512);
        }
      }
    }
    // no barrier here: next tile's first k-step barrier orders scan vs cs rewrite
    // (cs is rewritten only after 16 more barriers).
  }
  if (tid < 128 && fl) atomicOr(flags + b, 1);
#undef STAGE
}

// ---------------------------------------------------------------- fixup (rare path)
// Self-sufficient f32 GEMV fallback; runs only if a batch spiked (never here).
__global__ __launch_bounds__(512) void scan_fix(const float* __restrict__ x,
                                                const float* __restrict__ W,
                                                const float* __restrict__ bias,
                                                const float* __restrict__ R,
                                                const float* __restrict__ decay,
                                                float* __restrict__ out,
                                                const int* __restrict__ flags) {
  const int b = blockIdx.x;
  if (flags[b] == 0) return;
  const int o = threadIdx.x;
  __shared__ float xs[512];
  __shared__ int cnt;
  __shared__ int list[512];
  const float d = decay[o];
  const float om = 1.f - d;
  float v = 0.f, z = 0.f;
  const size_t zb  = (size_t)b * 512000 + o;
  const size_t svb = (size_t)b * 512512 + o;
  float* __restrict__ sv = out + SV_OFF;
  float* __restrict__ sz = out + SZ_OFF;
  sv[svb] = 0.f;
  sz[svb] = 0.f;
  if (o == 0) cnt = 0;
  __syncthreads();
  for (int t = 0; t < 1000; ++t) {
    xs[o] = x[((size_t)b * 1000 + t) * 512 + o];
    __syncthreads();
    float soma = bias[o];
    for (int i = 0; i < 512; ++i) soma += xs[i] * W[(size_t)o * 512 + i];
    const int n = cnt;
    for (int i = 0; i < n; ++i) soma += R[(size_t)o * 512 + list[i]];
    v = d * (v * (1.f - z)) + om * soma;
    z = (v >= 1.0f) ? 1.0f : 0.0f;
    out[zb + (size_t)t * 512] = z;
    sv[svb + (size_t)(t + 1) * 512] = v;
    sz[svb + (size_t)(t + 1) * 512] = z;
    __syncthreads();
    if (o == 0) cnt = 0;
    __syncthreads();
    if (z != 0.f) { const int q = atomicAdd(&cnt, 1); list[q] = o; }
    __syncthreads();
  }
}

extern "C" void kernel_launch(void* const* d_in, const int* in_sizes, int n_in,
                              void* d_out, int out_size, void* d_ws, size_t ws_size,
                              hipStream_t stream) {
  (void)in_sizes; (void)n_in; (void)out_size; (void)ws_size;
  const float* x     = (const float*)d_in[0];  // [64,1000,512]
  const float* W     = (const float*)d_in[1];  // [512,512]
  const float* bias  = (const float*)d_in[2];  // [512]
  const float* R     = (const float*)d_in[3];  // [512,512]
  const float* decay = (const float*)d_in[4];  // [512]
  float* out = (float*)d_out;

  char* ws = (char*)d_ws;
  unsigned short* xb = (unsigned short*)ws;                 // 65,536,000 B
  unsigned short* Wb = (unsigned short*)(ws + 65536000);    //    524,288 B
  int* flags         = (int*)(ws + 66060288);               //        256 B
  // (OOB-safe: b=63 tile-7 pad rows read <=25 KB into the Wb region)

  prep<<<1024, 256, 0, stream>>>(W, Wb, flags);
  cvt_x<<<16000, 256, 0, stream>>>(x, xb);
  fused<<<dim3(64, 4), 512, 0, stream>>>(xb, Wb, bias, decay, out, flags);
  scan_fix<<<64, 512, 0, stream>>>(x, W, bias, R, decay, out, flags);
}

// Round 6
// 526.946 us; speedup vs baseline: 1.1966x; 1.0059x over previous
//
#include <hip/hip_runtime.h>

// Problem constants (B=64, T=1000, IN=OUT=512)
//   outputs  zs     [64,1000,512]        -> d_out[0 .. 32768000)
//   states   v_full [64,1001,512]        -> d_out[32768000 .. 65568768)
//   states   z_full [64,1001,512]        -> d_out[65568768 .. 98369536)
#define SV_OFF 32768000
#define SZ_OFF 65568768

typedef __attribute__((ext_vector_type(8))) short bf16x8;
typedef __attribute__((ext_vector_type(4))) float f32x4;

__device__ __forceinline__ unsigned short f2bf(float f) {
  union { float f; unsigned u; } x; x.f = f;
  unsigned r = x.u + 0x7fffu + ((x.u >> 16) & 1u);  // RNE
  return (unsigned short)(r >> 16);
}

__device__ __forceinline__ void gl_lds16(const void* g, void* l) {
  __builtin_amdgcn_global_load_lds(
      (const __attribute__((address_space(1))) unsigned int*)g,
      (__attribute__((address_space(3))) unsigned int*)l, 16, 0, 0);
}

// ---------------------------------------------------------------- prep
__global__ __launch_bounds__(256) void prep(const float* __restrict__ W,
                                            unsigned short* __restrict__ Wb,
                                            int* __restrict__ flags) {
  const int idx = blockIdx.x * 256 + threadIdx.x;
  if (idx < 512 * 512) Wb[idx] = f2bf(W[idx]);
  if (idx < 64) flags[idx] = 0;
}

// ---------------------------------------------------------------- cvt_x
__global__ __launch_bounds__(256) void cvt_x(const float* __restrict__ x,
                                             unsigned short* __restrict__ xb) {
  const size_t i = ((size_t)blockIdx.x * 256 + threadIdx.x) * 8;
  const float4 a = *(const float4*)(x + i);
  const float4 b = *(const float4*)(x + i + 4);
  bf16x8 h;
  h[0] = (short)f2bf(a.x); h[1] = (short)f2bf(a.y);
  h[2] = (short)f2bf(a.z); h[3] = (short)f2bf(a.w);
  h[4] = (short)f2bf(b.x); h[5] = (short)f2bf(b.y);
  h[6] = (short)f2bf(b.z); h[7] = (short)f2bf(b.w);
  *(bf16x8*)(xb + i) = h;
}

// ---------------------------------------------------------------- fused GEMM+scan
// Grid (64,4), 640 threads (10 waves), 1 block/CU.
// Waves 0-7: MFMA GEMM only — depth-3 gl_lds pipeline, counted vmcnt(4)
//   that counts ONLY their own gl_lds (these waves never issue a global
//   store, so store drain can't poison the counted wait).
// Waves 8-9: scan tile T-1 in 8-timestep chunks inside tile T's 16 k-step
//   barrier intervals (chunk ~300cy << LDS-bound GEMM step) and issue all
//   NT output stores — the HBM write drain overlaps the GEMM.
__global__ __launch_bounds__(640, 1) void fused(
    const unsigned short* __restrict__ Ab,   // xb [64000,512] bf16
    const unsigned short* __restrict__ Wb,   // [512,512] bf16
    const float* __restrict__ bias,
    const float* __restrict__ decay,
    float* __restrict__ out,
    int* __restrict__ flags) {
  __shared__ unsigned short As[4][128][32];  // 32 KB (4-buf k-step pipeline)
  __shared__ unsigned short Bs[4][128][32];  // 32 KB
  __shared__ float cs[128][128];             // 64 KB (cur tile, lq-XOR swizzled)

  const int b    = blockIdx.x;
  const int o0   = blockIdx.y * 128;
  const int tid  = threadIdx.x;
  const int lane = tid & 63;
  const int wave = tid >> 6;
  const bool gemm = tid < 512;
  const int lr = lane & 15;
  const int lq = lane >> 4;
  const int wr = (wave >> 2) & 1;   // t-half of tile
  const int wc = wave & 3;          // o-quarter of slice

  // staging (gemm threads): 512 x 16B per gl_lds = one 8KB k-slice each for
  // As and Bs; linear LDS dest; global source 16B-slot XOR'd by (row&3).
  const int row0 = tid >> 2;                              // 0..127
  const int scol = ((tid & 3) * 16) ^ ((row0 & 3) << 4);  // swizzled src byte
  const char* abase = (const char*)Ab + (size_t)b * 1000 * 1024;
  const char* bbase = (const char*)Wb + (size_t)o0 * 1024;

#define STAGE(s_) do {                                                          \
    const int t0_ = ((s_) >> 4) * 128;                                          \
    const int kb_ = ((s_) & 15) * 64;                                           \
    const int bf_ = (s_) & 3;                                                   \
    gl_lds16(abase + (size_t)(t0_ + row0) * 1024 + kb_ + scol,                  \
             (char*)&As[bf_][0][0] + tid * 16);                                 \
    gl_lds16(bbase + (size_t)row0 * 1024 + kb_ + scol,                          \
             (char*)&Bs[bf_][0][0] + tid * 16);                                 \
  } while (0)

  // scan state (waves 8-9): lane so = tid-512 owns channel o0+so
  const int so = tid - 512;
  float v = 0.f, d = 0.f, om = 0.f, bv = 0.f;
  int fl = 0;
  if (!gemm) {
    d  = decay[o0 + so];
    om = 1.f - d;
    bv = bias[o0 + so];
    __builtin_nontemporal_store(0.f, out + SV_OFF + (size_t)b * 512512 + o0 + so);
    __builtin_nontemporal_store(0.f, out + SZ_OFF + (size_t)b * 512512 + o0 + so);
  } else {
    STAGE(0); STAGE(1); STAGE(2);   // prologue: 6 loads/wave in flight
  }

  int s = 0;
  for (int tile = 0; tile < 8; ++tile) {
    f32x4 acc[4][2] = {};
    for (int kk = 0; kk < 16; ++kk, ++s) {
      if (gemm)
        asm volatile("s_waitcnt vmcnt(4)" ::: "memory");  // own gl_lds only
      __builtin_amdgcn_s_barrier();
      __builtin_amdgcn_sched_barrier(0);
      if (gemm) {
        // wrap stages (s>=125) are dummies into already-consumed buffers:
        // keeps vmcnt(4) uniform and tail-race-free.
        STAGE((s + 3) & 127);
        const int bf_ = s & 3;
        const int fo = (lq ^ (lr & 3)) * 8;   // un-swizzle the source XOR
        bf16x8 af[4], bq[2];
#pragma unroll
        for (int i = 0; i < 4; ++i)
          af[i] = *(const bf16x8*)(&As[bf_][wr * 64 + i * 16 + lr][fo]);
#pragma unroll
        for (int j = 0; j < 2; ++j)
          bq[j] = *(const bf16x8*)(&Bs[bf_][wc * 32 + j * 16 + lr][fo]);
        __builtin_amdgcn_s_setprio(1);
#pragma unroll
        for (int i = 0; i < 4; ++i)
#pragma unroll
          for (int j = 0; j < 2; ++j)
            acc[i][j] = __builtin_amdgcn_mfma_f32_16x16x32_bf16(af[i], bq[j], acc[i][j], 0, 0, 0);
        __builtin_amdgcn_s_setprio(0);
      } else if (tile > 0) {
        // scan 8 timesteps of tile-1 (cs holds tile-1 until the pre-write
        // barrier below; chunks kk=0..15 cover t=0..127)
        const int pt0 = (tile - 1) * 128;
        const int tb = kk * 8;
        float* zp = out + ((size_t)b * 1000 + pt0 + tb) * 512 + o0 + so;
        float* vp = out + SV_OFF + ((size_t)b * 1001 + pt0 + tb + 1) * 512 + o0 + so;
        float* sp = out + SZ_OFF + ((size_t)b * 1001 + pt0 + tb + 1) * 512 + o0 + so;
#pragma unroll
        for (int u = 0; u < 8; ++u) {
          const int t = tb + u;
          const float c = cs[t][so ^ (((t >> 2) & 3) << 4)];
          v = d * v + om * (c + bv);   // exact reference op order (no-spike path)
          const float z = (v >= 1.0f) ? 1.0f : 0.0f;
          fl |= (v >= 1.0f);
          __builtin_nontemporal_store(z, zp + (size_t)u * 512);
          __builtin_nontemporal_store(v, vp + (size_t)u * 512);
          __builtin_nontemporal_store(z, sp + (size_t)u * 512);
        }
      }
    }
    __builtin_amdgcn_s_barrier();          // scan chunk 15 done reading cs
    __builtin_amdgcn_sched_barrier(0);
    if (gemm) {
      // acc -> cs. Writer col' = col ^ (lq<<4): write ~2-way, read ~2-way
      // (lq = (row>>2)&3 for every row this lane writes; readers recover
      //  col via t: stored col' = col ^ (((t>>2)&3)<<4)).
#pragma unroll
      for (int i = 0; i < 4; ++i)
#pragma unroll
        for (int j = 0; j < 2; ++j) {
          const int tb = wr * 64 + i * 16 + lq * 4;
          const int cc = (wc * 32 + j * 16 + lr) ^ (lq << 4);
#pragma unroll
          for (int r = 0; r < 4; ++r) cs[tb + r][cc] = acc[i][j][r];
        }
      asm volatile("s_waitcnt lgkmcnt(0)" ::: "memory");
    }
    __builtin_amdgcn_s_barrier();          // cs(tile) complete & visible
    __builtin_amdgcn_sched_barrier(0);
  }
  // epilogue: scan waves handle tile 7 (104 valid steps); GEMM waves exit.
  if (!gemm) {
    const int pt0 = 896;
    float* zp = out + ((size_t)b * 1000 + pt0) * 512 + o0 + so;
    float* vp = out + SV_OFF + ((size_t)b * 1001 + pt0 + 1) * 512 + o0 + so;
    float* sp = out + SZ_OFF + ((size_t)b * 1001 + pt0 + 1) * 512 + o0 + so;
    for (int t = 0; t < 104; ++t) {
      const float c = cs[t][so ^ (((t >> 2) & 3) << 4)];
      v = d * v + om * (c + bv);
      const float z = (v >= 1.0f) ? 1.0f : 0.0f;
      fl |= (v >= 1.0f);
      __builtin_nontemporal_store(z, zp + (size_t)t * 512);
      __builtin_nontemporal_store(v, vp + (size_t)t * 512);
      __builtin_nontemporal_store(z, sp + (size_t)t * 512);
    }
    if (fl) atomicOr(flags + b, 1);
  }
#undef STAGE
}

// ---------------------------------------------------------------- fixup (rare path)
// Self-sufficient f32 GEMV fallback; runs only if a batch spiked (never here).
__global__ __launch_bounds__(512) void scan_fix(const float* __restrict__ x,
                                                const float* __restrict__ W,
                                                const float* __restrict__ bias,
                                                const float* __restrict__ R,
                                                const float* __restrict__ decay,
                                                float* __restrict__ out,
                                                const int* __restrict__ flags) {
  const int b = blockIdx.x;
  if (flags[b] == 0) return;
  const int o = threadIdx.x;
  __shared__ float xs[512];
  __shared__ int cnt;
  __shared__ int list[512];
  const float d = decay[o];
  const float om = 1.f - d;
  float v = 0.f, z = 0.f;
  const size_t zb  = (size_t)b * 512000 + o;
  const size_t svb = (size_t)b * 512512 + o;
  float* __restrict__ sv = out + SV_OFF;
  float* __restrict__ sz = out + SZ_OFF;
  sv[svb] = 0.f;
  sz[svb] = 0.f;
  if (o == 0) cnt = 0;
  __syncthreads();
  for (int t = 0; t < 1000; ++t) {
    xs[o] = x[((size_t)b * 1000 + t) * 512 + o];
    __syncthreads();
    float soma = bias[o];
    for (int i = 0; i < 512; ++i) soma += xs[i] * W[(size_t)o * 512 + i];
    const int n = cnt;
    for (int i = 0; i < n; ++i) soma += R[(size_t)o * 512 + list[i]];
    v = d * (v * (1.f - z)) + om * soma;
    z = (v >= 1.0f) ? 1.0f : 0.0f;
    out[zb + (size_t)t * 512] = z;
    sv[svb + (size_t)(t + 1) * 512] = v;
    sz[svb + (size_t)(t + 1) * 512] = z;
    __syncthreads();
    if (o == 0) cnt = 0;
    __syncthreads();
    if (z != 0.f) { const int q = atomicAdd(&cnt, 1); list[q] = o; }
    __syncthreads();
  }
}

extern "C" void kernel_launch(void* const* d_in, const int* in_sizes, int n_in,
                              void* d_out, int out_size, void* d_ws, size_t ws_size,
                              hipStream_t stream) {
  (void)in_sizes; (void)n_in; (void)out_size; (void)ws_size;
  const float* x     = (const float*)d_in[0];  // [64,1000,512]
  const float* W     = (const float*)d_in[1];  // [512,512]
  const float* bias  = (const float*)d_in[2];  // [512]
  const float* R     = (const float*)d_in[3];  // [512,512]
  const float* decay = (const float*)d_in[4];  // [512]
  float* out = (float*)d_out;

  char* ws = (char*)d_ws;
  unsigned short* xb = (unsigned short*)ws;                 // 65,536,000 B
  unsigned short* Wb = (unsigned short*)(ws + 65536000);    //    524,288 B
  int* flags         = (int*)(ws + 66060288);               //        256 B
  // (OOB-safe: b=63 tile-7 pad rows read <=25 KB into the Wb region)

  prep<<<1024, 256, 0, stream>>>(W, Wb, flags);
  cvt_x<<<16000, 256, 0, stream>>>(x, xb);
  fused<<<dim3(64, 4), 640, 0, stream>>>(xb, Wb, bias, decay, out, flags);
  scan_fix<<<64, 512, 0, stream>>>(x, W, bias, R, decay, out, flags);
}